// Round 3
// baseline (1596.514 us; speedup 1.0000x reference)
//
#include <hip/hip_runtime.h>
#include <stdint.h>

// STAR fused forward via split-precision bf16x2 MFMA (gfx950), round 3.
// acc = Ahi*Bhi + Ahi*Blo + Alo*Bhi (fp32 MFMA accumulate) -> ~2^-16 rel err.
// Round-3 change: zero-VALU A-path.
//  - prep_x splits X once into row-major bf16 hi/lo planes in ws (A-frag =
//    two 16B loads; kills the per-j re-split that made round 2 VALU-bound).
//  - H0/H1 LDS as separate hi/lo u16 planes (A-frag = two ds_read_b128,
//    zero unpack VALU; split happens once on epilogue write).
// Weight B-frags pre-fused (sk*dk) in MFMA B-frag order; read straight from
// L2 with coalesced dwordx4; no barriers inside any K-loop.

namespace {

typedef __attribute__((ext_vector_type(8))) short bf16x8;
typedef __attribute__((ext_vector_type(4))) float f32x4;

union Frag { bf16x8 v; unsigned int u[4]; };

// ---- ws layout ----
constexpr size_t WS_XHI = 0;                  // 65536*512 u16 = 64 MiB
constexpr size_t WS_XLO = 67108864;           // 64 MiB
constexpr size_t WS_W   = 134217728;          // weights region (presplit mode)
// offsets inside the weights region:
constexpr size_t WO_L0 = 0;                   // 8*16*16 pairs * 2048B = 4 MiB
constexpr size_t WO_L1 = 4194304;             // 1 MiB
constexpr size_t WO_L2 = 5242880;             // 256 KiB
constexpr size_t WO_B0 = 5505024;             // 8*256 f32
constexpr size_t WO_B1 = 5513216;             // 8*128 f32
constexpr size_t WO_B2 = 5517312;             // 8*64  f32
constexpr size_t WO_END = 5519360;
constexpr size_t WS_FULL_END = WS_W + WO_END; // ~133.3 MiB

constexpr int PREP_TOTAL = 1048576 + 262144 + 65536 + 2048 + 1024 + 512;

__device__ __forceinline__ void splitpair(float a, float b,
                                          unsigned int& hi, unsigned int& lo) {
    unsigned int ua = __float_as_uint(a);
    unsigned int ub = __float_as_uint(b);
    unsigned int ha = ua & 0xffff0000u;
    unsigned int hb = ub & 0xffff0000u;
    float ra = a - __uint_as_float(ha);
    float rb = b - __uint_as_float(hb);
    hi = (ua >> 16) | hb;
    lo = (__float_as_uint(ra) >> 16) | (__float_as_uint(rb) & 0xffff0000u);
}

__device__ __forceinline__ void split1(float v, unsigned short& h, unsigned short& l) {
    unsigned int u = __float_as_uint(v);
    h = (unsigned short)(u >> 16);
    float r = v - __uint_as_float(u & 0xffff0000u);
    l = (unsigned short)(__float_as_uint(r) >> 16);
}

// ---------------- prep_x: split X -> bf16 hi/lo planes ----------------
__global__ void prep_x(const float* __restrict__ x,
                       unsigned short* __restrict__ xhi,
                       unsigned short* __restrict__ xlo) {
    size_t i = ((size_t)blockIdx.x * 256 + threadIdx.x) * 4;
    float4 v = *(const float4*)(x + i);
    ushort4 h, l;
    split1(v.x, h.x, l.x);
    split1(v.y, h.y, l.y);
    split1(v.z, h.z, l.z);
    split1(v.w, h.w, l.w);
    *(ushort4*)(xhi + i) = h;
    *(ushort4*)(xlo + i) = l;
}

// ---------------- prep_ws: fuse sk*dk -> hi/lo B-frag planes + biases --
__global__ void prep_ws(const float* __restrict__ sk0, const float* __restrict__ dk0,
                        const float* __restrict__ sk1, const float* __restrict__ dk1,
                        const float* __restrict__ sk2, const float* __restrict__ dk2,
                        const float* __restrict__ sb0, const float* __restrict__ db0,
                        const float* __restrict__ sb1, const float* __restrict__ db1,
                        const float* __restrict__ sb2, const float* __restrict__ db2,
                        char* __restrict__ wsw) {
    int tid = blockIdx.x * 256 + threadIdx.x;
    if (tid < 1048576) {                       // layer 0: [j][k<512][n<256]
        int n = tid & 255, k = (tid >> 8) & 511, j = tid >> 17;
        float wv = sk0[k * 256 + n] * dk0[(size_t)(j * 512 + k) * 256 + n];
        unsigned short h, l; split1(wv, h, l);
        int pair = (j * 16 + (k >> 5)) * 16 + (n >> 4);
        int lane = (n & 15) | (((k >> 3) & 3) << 4);
        size_t off = WO_L0 + (size_t)pair * 2048 + lane * 16 + (k & 7) * 2;
        *(unsigned short*)(wsw + off)        = h;
        *(unsigned short*)(wsw + off + 1024) = l;
    } else if (tid < 1310720) {                // layer 1: [j][k<256][n<128]
        int t = tid - 1048576;
        int n = t & 127, k = (t >> 7) & 255, j = t >> 15;
        float wv = sk1[k * 128 + n] * dk1[(size_t)(j * 256 + k) * 128 + n];
        unsigned short h, l; split1(wv, h, l);
        int pair = (j * 8 + (k >> 5)) * 8 + (n >> 4);
        int lane = (n & 15) | (((k >> 3) & 3) << 4);
        size_t off = WO_L1 + (size_t)pair * 2048 + lane * 16 + (k & 7) * 2;
        *(unsigned short*)(wsw + off)        = h;
        *(unsigned short*)(wsw + off + 1024) = l;
    } else if (tid < 1376256) {                // layer 2: [j][k<128][n<64]
        int t = tid - 1310720;
        int n = t & 63, k = (t >> 6) & 127, j = t >> 13;
        float wv = sk2[k * 64 + n] * dk2[(size_t)(j * 128 + k) * 64 + n];
        unsigned short h, l; split1(wv, h, l);
        int pair = (j * 4 + (k >> 5)) * 4 + (n >> 4);
        int lane = (n & 15) | (((k >> 3) & 3) << 4);
        size_t off = WO_L2 + (size_t)pair * 2048 + lane * 16 + (k & 7) * 2;
        *(unsigned short*)(wsw + off)        = h;
        *(unsigned short*)(wsw + off + 1024) = l;
    } else if (tid < 1378304) {                // bias0: 8*256
        int t = tid - 1376256;
        ((float*)(wsw + WO_B0))[t] = sb0[t & 255] + db0[t];
    } else if (tid < 1379328) {                // bias1: 8*128
        int t = tid - 1378304;
        ((float*)(wsw + WO_B1))[t] = sb1[t & 127] + db1[t];
    } else if (tid < PREP_TOTAL) {             // bias2: 8*64
        int t = tid - 1379328;
        ((float*)(wsw + WO_B2))[t] = sb2[t & 63] + db2[t];
    }
}

// ---------------- main kernel: 256 thr (4 waves), 32 rows/block -------
// PRESPLIT=true: A-frags for phase 0 come from xhi/xlo planes (no VALU).
// PRESPLIT=false: fallback, split x on the fly (round-2 style).
template<bool PRESPLIT>
__global__ __launch_bounds__(256, 3) void star_mfma(
    const unsigned short* __restrict__ xhi,
    const unsigned short* __restrict__ xlo,
    const float* __restrict__ x,
    const float* __restrict__ ind,
    const char* __restrict__ wsw,
    float* __restrict__ out)
{
    __shared__ unsigned short H0hi[32 * 264];   // [m][n], pad 256->264
    __shared__ unsigned short H0lo[32 * 264];
    __shared__ unsigned short H1hi[32 * 136];   // [m][n], pad 128->136
    __shared__ unsigned short H1lo[32 * 136];
    __shared__ float indS[8 * 33];

    const int tid  = threadIdx.x;
    const int w    = tid >> 6;      // wave 0..3 (n-split in every phase)
    const int lane = tid & 63;
    const int c    = lane & 15;
    const int q    = lane >> 4;
    const int b0   = blockIdx.x * 32;

    const char* wB0 = wsw + WO_L0;
    const char* wB1 = wsw + WO_L1;
    const char* wB2 = wsw + WO_L2;
    const float* bias0 = (const float*)(wsw + WO_B0);
    const float* bias1 = (const float*)(wsw + WO_B1);
    const float* bias2 = (const float*)(wsw + WO_B2);

    // stage indicator (transposed, padded): indS[j][m]
    indS[(tid & 7) * 33 + (tid >> 3)] = ind[(size_t)b0 * 8 + tid];

    const f32x4 z = {0.f, 0.f, 0.f, 0.f};
    f32x4 oacc[2]; oacc[0] = z; oacc[1] = z;

    __syncthreads();

    for (int j = 0; j < 8; ++j) {
        // ================= phase 0: X[32,512] @ W0[512,256] ================
        f32x4 acc0[2][4];
#pragma unroll
        for (int mt = 0; mt < 2; ++mt)
#pragma unroll
            for (int ntl = 0; ntl < 4; ++ntl) acc0[mt][ntl] = z;

        for (int kc = 0; kc < 16; ++kc) {
            Frag Ahi[2], Alo[2];
#pragma unroll
            for (int mt = 0; mt < 2; ++mt) {
                if (PRESPLIT) {
                    const size_t off = (size_t)(b0 + mt * 16 + c) * 512 + kc * 32 + q * 8;
                    *(uint4*)Ahi[mt].u = *(const uint4*)(xhi + off);
                    *(uint4*)Alo[mt].u = *(const uint4*)(xlo + off);
                } else {
                    const float* ap = x + (size_t)(b0 + mt * 16 + c) * 512 + kc * 32 + q * 8;
                    float4 a0 = *(const float4*)ap;
                    float4 a1 = *(const float4*)(ap + 4);
                    splitpair(a0.x, a0.y, Ahi[mt].u[0], Alo[mt].u[0]);
                    splitpair(a0.z, a0.w, Ahi[mt].u[1], Alo[mt].u[1]);
                    splitpair(a1.x, a1.y, Ahi[mt].u[2], Alo[mt].u[2]);
                    splitpair(a1.z, a1.w, Ahi[mt].u[3], Alo[mt].u[3]);
                }
            }
#pragma unroll
            for (int ntl = 0; ntl < 4; ++ntl) {
                const int nt = w * 4 + ntl;
                const char* pb = wB0 + ((size_t)((j * 16 + kc) * 16 + nt) * 2048) + lane * 16;
                Frag Bhi, Blo;
                *(uint4*)Bhi.u = *(const uint4*)pb;
                *(uint4*)Blo.u = *(const uint4*)(pb + 1024);
#pragma unroll
                for (int mt = 0; mt < 2; ++mt) {
                    acc0[mt][ntl] = __builtin_amdgcn_mfma_f32_16x16x32_bf16(Ahi[mt].v, Bhi.v, acc0[mt][ntl], 0, 0, 0);
                    acc0[mt][ntl] = __builtin_amdgcn_mfma_f32_16x16x32_bf16(Ahi[mt].v, Blo.v, acc0[mt][ntl], 0, 0, 0);
                    acc0[mt][ntl] = __builtin_amdgcn_mfma_f32_16x16x32_bf16(Alo[mt].v, Bhi.v, acc0[mt][ntl], 0, 0, 0);
                }
            }
        }
        // epilogue 0: bias + relu -> split planes H0hi/H0lo [m][n]
#pragma unroll
        for (int ntl = 0; ntl < 4; ++ntl) {
            const float bv = bias0[j * 256 + w * 64 + ntl * 16 + c];
#pragma unroll
            for (int mt = 0; mt < 2; ++mt)
#pragma unroll
                for (int r = 0; r < 4; ++r) {
                    float v = acc0[mt][ntl][r] + bv;
                    v = fmaxf(v, 0.f);
                    unsigned short h, l; split1(v, h, l);
                    const int idx = (mt * 16 + q * 4 + r) * 264 + w * 64 + ntl * 16 + c;
                    H0hi[idx] = h;
                    H0lo[idx] = l;
                }
        }
        __syncthreads();

        // ================= phase 1: H0[32,256] @ W1[256,128] ===============
        f32x4 acc1[2][2];
#pragma unroll
        for (int mt = 0; mt < 2; ++mt)
#pragma unroll
            for (int ntl = 0; ntl < 2; ++ntl) acc1[mt][ntl] = z;

        for (int kc = 0; kc < 8; ++kc) {
            Frag Ahi[2], Alo[2];
#pragma unroll
            for (int mt = 0; mt < 2; ++mt) {
                const int off = (mt * 16 + c) * 264 + kc * 32 + q * 8;
                *(uint4*)Ahi[mt].u = *(const uint4*)(H0hi + off);
                *(uint4*)Alo[mt].u = *(const uint4*)(H0lo + off);
            }
#pragma unroll
            for (int ntl = 0; ntl < 2; ++ntl) {
                const int nt = w * 2 + ntl;
                const char* pb = wB1 + ((size_t)((j * 8 + kc) * 8 + nt) * 2048) + lane * 16;
                Frag Bhi, Blo;
                *(uint4*)Bhi.u = *(const uint4*)pb;
                *(uint4*)Blo.u = *(const uint4*)(pb + 1024);
#pragma unroll
                for (int mt = 0; mt < 2; ++mt) {
                    acc1[mt][ntl] = __builtin_amdgcn_mfma_f32_16x16x32_bf16(Ahi[mt].v, Bhi.v, acc1[mt][ntl], 0, 0, 0);
                    acc1[mt][ntl] = __builtin_amdgcn_mfma_f32_16x16x32_bf16(Ahi[mt].v, Blo.v, acc1[mt][ntl], 0, 0, 0);
                    acc1[mt][ntl] = __builtin_amdgcn_mfma_f32_16x16x32_bf16(Alo[mt].v, Bhi.v, acc1[mt][ntl], 0, 0, 0);
                }
            }
        }
        // epilogue 1 -> split planes H1hi/H1lo
#pragma unroll
        for (int ntl = 0; ntl < 2; ++ntl) {
            const float bv = bias1[j * 128 + w * 32 + ntl * 16 + c];
#pragma unroll
            for (int mt = 0; mt < 2; ++mt)
#pragma unroll
                for (int r = 0; r < 4; ++r) {
                    float v = acc1[mt][ntl][r] + bv;
                    v = fmaxf(v, 0.f);
                    unsigned short h, l; split1(v, h, l);
                    const int idx = (mt * 16 + q * 4 + r) * 136 + w * 32 + ntl * 16 + c;
                    H1hi[idx] = h;
                    H1lo[idx] = l;
                }
        }
        __syncthreads();

        // ================= phase 2: H1[32,128] @ W2[128,64], mix ==========
        f32x4 acc2[2]; acc2[0] = z; acc2[1] = z;

        for (int kc = 0; kc < 4; ++kc) {
            Frag Ahi[2], Alo[2];
#pragma unroll
            for (int mt = 0; mt < 2; ++mt) {
                const int off = (mt * 16 + c) * 136 + kc * 32 + q * 8;
                *(uint4*)Ahi[mt].u = *(const uint4*)(H1hi + off);
                *(uint4*)Alo[mt].u = *(const uint4*)(H1lo + off);
            }
            const char* pb = wB2 + ((size_t)((j * 4 + kc) * 4 + w) * 2048) + lane * 16;
            Frag Bhi, Blo;
            *(uint4*)Bhi.u = *(const uint4*)pb;
            *(uint4*)Blo.u = *(const uint4*)(pb + 1024);
#pragma unroll
            for (int mt = 0; mt < 2; ++mt) {
                acc2[mt] = __builtin_amdgcn_mfma_f32_16x16x32_bf16(Ahi[mt].v, Bhi.v, acc2[mt], 0, 0, 0);
                acc2[mt] = __builtin_amdgcn_mfma_f32_16x16x32_bf16(Ahi[mt].v, Blo.v, acc2[mt], 0, 0, 0);
                acc2[mt] = __builtin_amdgcn_mfma_f32_16x16x32_bf16(Alo[mt].v, Bhi.v, acc2[mt], 0, 0, 0);
            }
        }
        // epilogue 2: bias + relu + indicator mix into oacc (registers)
        {
            const float bv = bias2[j * 64 + w * 16 + c];
#pragma unroll
            for (int mt = 0; mt < 2; ++mt)
#pragma unroll
                for (int r = 0; r < 4; ++r) {
                    float v = acc2[mt][r] + bv;
                    v = fmaxf(v, 0.f);
                    oacc[mt][r] = fmaf(indS[j * 33 + mt * 16 + q * 4 + r], v, oacc[mt][r]);
                }
        }
        // next-j H0/H1 write hazards are covered by the two barriers above.
    }

    // store: out[b0 + m][w*16 + c]
#pragma unroll
    for (int mt = 0; mt < 2; ++mt)
#pragma unroll
        for (int r = 0; r < 4; ++r)
            out[(size_t)(b0 + mt * 16 + q * 4 + r) * 64 + w * 16 + c] = oacc[mt][r];
}

} // namespace

extern "C" void kernel_launch(void* const* d_in, const int* in_sizes, int n_in,
                              void* d_out, int out_size, void* d_ws, size_t ws_size,
                              hipStream_t stream) {
    const float* x   = (const float*)d_in[0];
    const float* ind = (const float*)d_in[1];
    const float* sk0 = (const float*)d_in[2];
    const float* sb0 = (const float*)d_in[3];
    const float* dk0 = (const float*)d_in[4];
    const float* db0 = (const float*)d_in[5];
    const float* sk1 = (const float*)d_in[6];
    const float* sb1 = (const float*)d_in[7];
    const float* dk1 = (const float*)d_in[8];
    const float* db1 = (const float*)d_in[9];
    const float* sk2 = (const float*)d_in[10];
    const float* sb2 = (const float*)d_in[11];
    const float* dk2 = (const float*)d_in[12];
    const float* db2 = (const float*)d_in[13];
    char* ws   = (char*)d_ws;
    float* out = (float*)d_out;

    const bool presplit = (ws_size >= WS_FULL_END);
    char* wsw = presplit ? (ws + WS_W) : ws;

    prep_ws<<<dim3((PREP_TOTAL + 255) / 256), dim3(256), 0, stream>>>(
        sk0, dk0, sk1, dk1, sk2, dk2, sb0, db0, sb1, db1, sb2, db2, wsw);

    if (presplit) {
        unsigned short* xhi = (unsigned short*)(ws + WS_XHI);
        unsigned short* xlo = (unsigned short*)(ws + WS_XLO);
        prep_x<<<dim3(32768), dim3(256), 0, stream>>>(x, xhi, xlo);
        star_mfma<true><<<dim3(2048), dim3(256), 0, stream>>>(xhi, xlo, x, ind, wsw, out);
    } else {
        star_mfma<false><<<dim3(2048), dim3(256), 0, stream>>>(nullptr, nullptr, x, ind, wsw, out);
    }
}

// Round 4
// 1028.239 us; speedup vs baseline: 1.5527x; 1.5527x over previous
//
#include <hip/hip_runtime.h>
#include <stdint.h>

// STAR fused forward via split-precision bf16x2 MFMA (gfx950), round 4.
// acc = Ahi*Bhi + Ahi*Blo + Alo*Bhi (fp32 MFMA accumulate) -> ~2^-16 rel err.
// Round-4 changes vs round 2 (round 3's presplit-X regressed: HBM round trip):
//  - TB=64 rows/block, 512 threads (8 waves: 2 m-groups x 4 n-groups),
//    1024 blocks -> halves total weight B-frag L2 traffic.
//  - H1 LDS aliased into H0 region (+2 barriers/j) -> 68.6 KB LDS ->
//    2 blocks/CU = 16 waves/CU (was 12).
//  - X split back to on-the-fly VALU (overlaps MFMA; no HBM cost).

namespace {

typedef __attribute__((ext_vector_type(8))) short bf16x8;
typedef __attribute__((ext_vector_type(4))) float f32x4;

union Frag { bf16x8 v; unsigned int u[4]; };

// ---- ws layout (weights region only) ----
constexpr size_t WO_L0 = 0;                   // 8*16*16 pairs * 2048B = 4 MiB
constexpr size_t WO_L1 = 4194304;             // 1 MiB
constexpr size_t WO_L2 = 5242880;             // 256 KiB
constexpr size_t WO_B0 = 5505024;             // 8*256 f32
constexpr size_t WO_B1 = 5513216;             // 8*128 f32
constexpr size_t WO_B2 = 5517312;             // 8*64  f32

constexpr int PREP_TOTAL = 1048576 + 262144 + 65536 + 2048 + 1024 + 512;

__device__ __forceinline__ void splitpair(float a, float b,
                                          unsigned int& hi, unsigned int& lo) {
    unsigned int ua = __float_as_uint(a);
    unsigned int ub = __float_as_uint(b);
    unsigned int ha = ua & 0xffff0000u;
    unsigned int hb = ub & 0xffff0000u;
    float ra = a - __uint_as_float(ha);
    float rb = b - __uint_as_float(hb);
    hi = (ua >> 16) | hb;
    lo = (__float_as_uint(ra) >> 16) | (__float_as_uint(rb) & 0xffff0000u);
}

__device__ __forceinline__ unsigned int packsplit(float v) {
    unsigned int u = __float_as_uint(v);
    unsigned int h = u & 0xffff0000u;
    float r = v - __uint_as_float(h);
    return h | (__float_as_uint(r) >> 16);
}

__device__ __forceinline__ void unpack2(unsigned int e0, unsigned int e1,
                                        unsigned int& hi, unsigned int& lo) {
    hi = (e0 >> 16) | (e1 & 0xffff0000u);
    lo = (e0 & 0xffffu) | (e1 << 16);
}

__device__ __forceinline__ void split1(float v, unsigned short& h, unsigned short& l) {
    unsigned int u = __float_as_uint(v);
    h = (unsigned short)(u >> 16);
    float r = v - __uint_as_float(u & 0xffff0000u);
    l = (unsigned short)(__float_as_uint(r) >> 16);
}

// ---------------- prep_ws: fuse sk*dk -> hi/lo B-frag planes + biases --
__global__ void prep_ws(const float* __restrict__ sk0, const float* __restrict__ dk0,
                        const float* __restrict__ sk1, const float* __restrict__ dk1,
                        const float* __restrict__ sk2, const float* __restrict__ dk2,
                        const float* __restrict__ sb0, const float* __restrict__ db0,
                        const float* __restrict__ sb1, const float* __restrict__ db1,
                        const float* __restrict__ sb2, const float* __restrict__ db2,
                        char* __restrict__ wsw) {
    int tid = blockIdx.x * 256 + threadIdx.x;
    if (tid < 1048576) {                       // layer 0: [j][k<512][n<256]
        int n = tid & 255, k = (tid >> 8) & 511, j = tid >> 17;
        float wv = sk0[k * 256 + n] * dk0[(size_t)(j * 512 + k) * 256 + n];
        unsigned short h, l; split1(wv, h, l);
        int pair = (j * 16 + (k >> 5)) * 16 + (n >> 4);
        int lane = (n & 15) | (((k >> 3) & 3) << 4);
        size_t off = WO_L0 + (size_t)pair * 2048 + lane * 16 + (k & 7) * 2;
        *(unsigned short*)(wsw + off)        = h;
        *(unsigned short*)(wsw + off + 1024) = l;
    } else if (tid < 1310720) {                // layer 1: [j][k<256][n<128]
        int t = tid - 1048576;
        int n = t & 127, k = (t >> 7) & 255, j = t >> 15;
        float wv = sk1[k * 128 + n] * dk1[(size_t)(j * 256 + k) * 128 + n];
        unsigned short h, l; split1(wv, h, l);
        int pair = (j * 8 + (k >> 5)) * 8 + (n >> 4);
        int lane = (n & 15) | (((k >> 3) & 3) << 4);
        size_t off = WO_L1 + (size_t)pair * 2048 + lane * 16 + (k & 7) * 2;
        *(unsigned short*)(wsw + off)        = h;
        *(unsigned short*)(wsw + off + 1024) = l;
    } else if (tid < 1376256) {                // layer 2: [j][k<128][n<64]
        int t = tid - 1310720;
        int n = t & 63, k = (t >> 6) & 127, j = t >> 13;
        float wv = sk2[k * 64 + n] * dk2[(size_t)(j * 128 + k) * 64 + n];
        unsigned short h, l; split1(wv, h, l);
        int pair = (j * 4 + (k >> 5)) * 4 + (n >> 4);
        int lane = (n & 15) | (((k >> 3) & 3) << 4);
        size_t off = WO_L2 + (size_t)pair * 2048 + lane * 16 + (k & 7) * 2;
        *(unsigned short*)(wsw + off)        = h;
        *(unsigned short*)(wsw + off + 1024) = l;
    } else if (tid < 1378304) {                // bias0: 8*256
        int t = tid - 1376256;
        ((float*)(wsw + WO_B0))[t] = sb0[t & 255] + db0[t];
    } else if (tid < 1379328) {                // bias1: 8*128
        int t = tid - 1378304;
        ((float*)(wsw + WO_B1))[t] = sb1[t & 127] + db1[t];
    } else if (tid < PREP_TOTAL) {             // bias2: 8*64
        int t = tid - 1379328;
        ((float*)(wsw + WO_B2))[t] = sb2[t & 63] + db2[t];
    }
}

// ---------------- main kernel: 512 thr (8 waves), 64 rows/block -------
__global__ __launch_bounds__(512, 4) void star_mfma(
    const float* __restrict__ x,    // [65536,512]
    const float* __restrict__ ind,  // [65536,8]
    const char* __restrict__ wsw,
    float* __restrict__ out)        // [65536,64]
{
    // H0: packed hi|lo u32, [m<64][n<256], pad 256->260.  66560 B.
    // H1 aliases the same region: [m<64][n<128], pad 128->132.  33792 B.
    __shared__ unsigned int H0s[64 * 260];
    __shared__ float indS[8 * 65];

    const int tid  = threadIdx.x;
    const int w    = tid >> 6;      // 0..7
    const int wm   = w >> 2;        // m-group 0..1 (32 rows each)
    const int wn   = w & 3;         // n-group 0..3
    const int lane = tid & 63;
    const int c    = lane & 15;
    const int q    = lane >> 4;
    const int b0   = blockIdx.x * 64;

    const char* wB0 = wsw + WO_L0;
    const char* wB1 = wsw + WO_L1;
    const char* wB2 = wsw + WO_L2;
    const float* bias0 = (const float*)(wsw + WO_B0);
    const float* bias1 = (const float*)(wsw + WO_B1);
    const float* bias2 = (const float*)(wsw + WO_B2);

    // stage indicator (transposed, padded): indS[j][m]; 512 elems, 1/thread.
    // First read of indS is after the j=0 barriers -> no extra barrier needed.
    indS[(tid & 7) * 65 + (tid >> 3)] = ind[(size_t)b0 * 8 + tid];

    const f32x4 z = {0.f, 0.f, 0.f, 0.f};
    f32x4 oacc[2]; oacc[0] = z; oacc[1] = z;

    for (int j = 0; j < 8; ++j) {
        // ========== phase 0: X[64,512] @ W0[512,256]  (no LDS use) =========
        f32x4 acc0[2][4];
#pragma unroll
        for (int mt = 0; mt < 2; ++mt)
#pragma unroll
            for (int ntl = 0; ntl < 4; ++ntl) acc0[mt][ntl] = z;

        for (int kc = 0; kc < 16; ++kc) {
            Frag Ahi[2], Alo[2];
#pragma unroll
            for (int mt = 0; mt < 2; ++mt) {
                const float* ap = x + (size_t)(b0 + wm * 32 + mt * 16 + c) * 512 + kc * 32 + q * 8;
                float4 a0 = *(const float4*)ap;
                float4 a1 = *(const float4*)(ap + 4);
                splitpair(a0.x, a0.y, Ahi[mt].u[0], Alo[mt].u[0]);
                splitpair(a0.z, a0.w, Ahi[mt].u[1], Alo[mt].u[1]);
                splitpair(a1.x, a1.y, Ahi[mt].u[2], Alo[mt].u[2]);
                splitpair(a1.z, a1.w, Ahi[mt].u[3], Alo[mt].u[3]);
            }
#pragma unroll
            for (int ntl = 0; ntl < 4; ++ntl) {
                const int nt = wn * 4 + ntl;
                const char* pb = wB0 + ((size_t)((j * 16 + kc) * 16 + nt) * 2048) + lane * 16;
                Frag Bhi, Blo;
                *(uint4*)Bhi.u = *(const uint4*)pb;
                *(uint4*)Blo.u = *(const uint4*)(pb + 1024);
#pragma unroll
                for (int mt = 0; mt < 2; ++mt) {
                    acc0[mt][ntl] = __builtin_amdgcn_mfma_f32_16x16x32_bf16(Ahi[mt].v, Bhi.v, acc0[mt][ntl], 0, 0, 0);
                    acc0[mt][ntl] = __builtin_amdgcn_mfma_f32_16x16x32_bf16(Ahi[mt].v, Blo.v, acc0[mt][ntl], 0, 0, 0);
                    acc0[mt][ntl] = __builtin_amdgcn_mfma_f32_16x16x32_bf16(Alo[mt].v, Bhi.v, acc0[mt][ntl], 0, 0, 0);
                }
            }
        }

        // B1: prior j's phase-2 reads of the aliased region must be done
        // before we overwrite it (also orders j=0 ind staging, vacuously).
        __syncthreads();

        // epilogue 0: bias + relu -> H0s[m][n] packed
#pragma unroll
        for (int ntl = 0; ntl < 4; ++ntl) {
            const float bv = bias0[j * 256 + wn * 64 + ntl * 16 + c];
#pragma unroll
            for (int mt = 0; mt < 2; ++mt)
#pragma unroll
                for (int r = 0; r < 4; ++r) {
                    float v = acc0[mt][ntl][r] + bv;
                    v = fmaxf(v, 0.f);
                    H0s[(wm * 32 + mt * 16 + q * 4 + r) * 260 + wn * 64 + ntl * 16 + c] = packsplit(v);
                }
        }
        __syncthreads();   // B2: H0 written -> phase-1 reads

        // ========== phase 1: H0[64,256] @ W1[256,128] ======================
        f32x4 acc1[2][2];
#pragma unroll
        for (int mt = 0; mt < 2; ++mt)
#pragma unroll
            for (int ntl = 0; ntl < 2; ++ntl) acc1[mt][ntl] = z;

        for (int kc = 0; kc < 8; ++kc) {
            Frag Ahi[2], Alo[2];
#pragma unroll
            for (int mt = 0; mt < 2; ++mt) {
                const unsigned int* hp = &H0s[(wm * 32 + mt * 16 + c) * 260 + kc * 32 + q * 8];
                uint4 e0 = *(const uint4*)hp;
                uint4 e1 = *(const uint4*)(hp + 4);
                unpack2(e0.x, e0.y, Ahi[mt].u[0], Alo[mt].u[0]);
                unpack2(e0.z, e0.w, Ahi[mt].u[1], Alo[mt].u[1]);
                unpack2(e1.x, e1.y, Ahi[mt].u[2], Alo[mt].u[2]);
                unpack2(e1.z, e1.w, Ahi[mt].u[3], Alo[mt].u[3]);
            }
#pragma unroll
            for (int ntl = 0; ntl < 2; ++ntl) {
                const int nt = wn * 2 + ntl;
                const char* pb = wB1 + ((size_t)((j * 8 + kc) * 8 + nt) * 2048) + lane * 16;
                Frag Bhi, Blo;
                *(uint4*)Bhi.u = *(const uint4*)pb;
                *(uint4*)Blo.u = *(const uint4*)(pb + 1024);
#pragma unroll
                for (int mt = 0; mt < 2; ++mt) {
                    acc1[mt][ntl] = __builtin_amdgcn_mfma_f32_16x16x32_bf16(Ahi[mt].v, Bhi.v, acc1[mt][ntl], 0, 0, 0);
                    acc1[mt][ntl] = __builtin_amdgcn_mfma_f32_16x16x32_bf16(Ahi[mt].v, Blo.v, acc1[mt][ntl], 0, 0, 0);
                    acc1[mt][ntl] = __builtin_amdgcn_mfma_f32_16x16x32_bf16(Alo[mt].v, Bhi.v, acc1[mt][ntl], 0, 0, 0);
                }
            }
        }
        __syncthreads();   // B3: phase-1 H0 reads done -> ep1 may overwrite (alias)

        // epilogue 1 -> H1 (aliased into H0s region), [m][n<128] pad 132
#pragma unroll
        for (int ntl = 0; ntl < 2; ++ntl) {
            const float bv = bias1[j * 128 + wn * 32 + ntl * 16 + c];
#pragma unroll
            for (int mt = 0; mt < 2; ++mt)
#pragma unroll
                for (int r = 0; r < 4; ++r) {
                    float v = acc1[mt][ntl][r] + bv;
                    v = fmaxf(v, 0.f);
                    H0s[(wm * 32 + mt * 16 + q * 4 + r) * 132 + wn * 32 + ntl * 16 + c] = packsplit(v);
                }
        }
        __syncthreads();   // B4: H1 written -> phase-2 reads

        // ========== phase 2: H1[64,128] @ W2[128,64], mix ==================
        f32x4 acc2[2]; acc2[0] = z; acc2[1] = z;

        for (int kc = 0; kc < 4; ++kc) {
            Frag Ahi[2], Alo[2];
#pragma unroll
            for (int mt = 0; mt < 2; ++mt) {
                const unsigned int* hp = &H0s[(wm * 32 + mt * 16 + c) * 132 + kc * 32 + q * 8];
                uint4 e0 = *(const uint4*)hp;
                uint4 e1 = *(const uint4*)(hp + 4);
                unpack2(e0.x, e0.y, Ahi[mt].u[0], Alo[mt].u[0]);
                unpack2(e0.z, e0.w, Ahi[mt].u[1], Alo[mt].u[1]);
                unpack2(e1.x, e1.y, Ahi[mt].u[2], Alo[mt].u[2]);
                unpack2(e1.z, e1.w, Ahi[mt].u[3], Alo[mt].u[3]);
            }
            const char* pb = wB2 + ((size_t)((j * 4 + kc) * 4 + wn) * 2048) + lane * 16;
            Frag Bhi, Blo;
            *(uint4*)Bhi.u = *(const uint4*)pb;
            *(uint4*)Blo.u = *(const uint4*)(pb + 1024);
#pragma unroll
            for (int mt = 0; mt < 2; ++mt) {
                acc2[mt] = __builtin_amdgcn_mfma_f32_16x16x32_bf16(Ahi[mt].v, Bhi.v, acc2[mt], 0, 0, 0);
                acc2[mt] = __builtin_amdgcn_mfma_f32_16x16x32_bf16(Ahi[mt].v, Blo.v, acc2[mt], 0, 0, 0);
                acc2[mt] = __builtin_amdgcn_mfma_f32_16x16x32_bf16(Alo[mt].v, Bhi.v, acc2[mt], 0, 0, 0);
            }
        }
        // epilogue 2: bias + relu + indicator mix into oacc (registers).
        // Next overwrite of the aliased region happens after B1 of next j.
        {
            const float bv = bias2[j * 64 + wn * 16 + c];
#pragma unroll
            for (int mt = 0; mt < 2; ++mt)
#pragma unroll
                for (int r = 0; r < 4; ++r) {
                    float v = acc2[mt][r] + bv;
                    v = fmaxf(v, 0.f);
                    oacc[mt][r] = fmaf(indS[j * 65 + wm * 32 + mt * 16 + q * 4 + r], v, oacc[mt][r]);
                }
        }
    }

    // store: out[b0 + wm*32 + mt*16 + q*4 + r][wn*16 + c]
#pragma unroll
    for (int mt = 0; mt < 2; ++mt)
#pragma unroll
        for (int r = 0; r < 4; ++r)
            out[(size_t)(b0 + wm * 32 + mt * 16 + q * 4 + r) * 64 + wn * 16 + c] = oacc[mt][r];
}

} // namespace

extern "C" void kernel_launch(void* const* d_in, const int* in_sizes, int n_in,
                              void* d_out, int out_size, void* d_ws, size_t ws_size,
                              hipStream_t stream) {
    const float* x   = (const float*)d_in[0];
    const float* ind = (const float*)d_in[1];
    const float* sk0 = (const float*)d_in[2];
    const float* sb0 = (const float*)d_in[3];
    const float* dk0 = (const float*)d_in[4];
    const float* db0 = (const float*)d_in[5];
    const float* sk1 = (const float*)d_in[6];
    const float* sb1 = (const float*)d_in[7];
    const float* dk1 = (const float*)d_in[8];
    const float* db1 = (const float*)d_in[9];
    const float* sk2 = (const float*)d_in[10];
    const float* sb2 = (const float*)d_in[11];
    const float* dk2 = (const float*)d_in[12];
    const float* db2 = (const float*)d_in[13];
    char* wsw  = (char*)d_ws;      // ~5.3 MiB used
    float* out = (float*)d_out;

    prep_ws<<<dim3((PREP_TOTAL + 255) / 256), dim3(256), 0, stream>>>(
        sk0, dk0, sk1, dk1, sk2, dk2, sb0, db0, sb1, db1, sb2, db2, wsw);

    star_mfma<<<dim3(1024), dim3(512), 0, stream>>>(x, ind, wsw, out);
}